// Round 4
// baseline (736.841 us; speedup 1.0000x reference)
//
#include <hip/hip_runtime.h>
#include <hip/hip_bf16.h>
#include <math.h>

#define OBS 512
#define MSG 2048
#define TAU 576
#define TAUP 640      // padded taus row stride
#define QN 16320
#define X2W 16896
#define INW 3136
#define PIW 2560

typedef short short8v __attribute__((ext_vector_type(8)));
typedef float f32x4 __attribute__((ext_vector_type(4)));

__device__ inline unsigned bfbits(float x) {
  __hip_bfloat16 h = __float2bfloat16(x);
  return (unsigned)*reinterpret_cast<unsigned short*>(&h);
}

__device__ inline void gload16(const void* g, void* l) {
  __builtin_amdgcn_global_load_lds((__attribute__((address_space(1))) void*)(g),
                                   (__attribute__((address_space(3))) void*)(l), 16, 0, 0);
}

// ---------------- bf16 MFMA NT matmul, BM=256, BN=64, BK=64, dbuf, 8 waves -----------
// C[m,n] = act(sum_k A[m,k]*W[n,k] + bias[n]). Weights fetched exactly once (one m-block
// covers M=256). DUAL: blockIdx.z picks set (GRU gi/gh pair). ATOMIC: split-K partials.
struct MMSet {
  const __hip_bfloat16* A;
  const __hip_bfloat16* W;
  const float* bias;
  float* C;
  __hip_bfloat16* Cb;
  int lda, ldw, ldc, ldcb;
};

template<int ACT, bool ATOMIC, bool DUAL>
__global__ __launch_bounds__(512)
void k_mm(MMSet s0, MMSet s1, int Nlim, int kSteps)
{
  __shared__ __hip_bfloat16 As[2][256 * 64];
  __shared__ __hip_bfloat16 Bs[2][64 * 64];
  const MMSet S = (DUAL && blockIdx.z) ? s1 : s0;
  const int tid = threadIdx.x;
  const int lane = tid & 63;
  const int wid = tid >> 6;
  const int m0 = blockIdx.y * 256;
  const int n0 = blockIdx.x * 64;
  const size_t k0 = ATOMIC ? (size_t)blockIdx.z * kSteps * 64 : 0;

  const __hip_bfloat16* Ab = S.A + (size_t)m0 * S.lda + k0;
  const __hip_bfloat16* Bb = S.W + (size_t)n0 * S.ldw + k0;

  // staging: A-tile 256x64 (2048 chunks of 16B, 4 rounds), B-tile 64x64 (512 chunks, 1 round)
  // LDS dest linear in chunk index; global source col-chunk XOR-swizzled by (row&7).
  int arow[4], acol[4], adst[4];
#pragma unroll
  for (int r = 0; r < 4; ++r) {
    int chunk = r * 512 + tid;
    arow[r] = chunk >> 3;
    acol[r] = ((chunk & 7) ^ (arow[r] & 7)) * 8;
    adst[r] = chunk * 8;
  }
  const int brow = tid >> 3;
  const int bcol = ((tid & 7) ^ (brow & 7)) * 8;
  const int bdst = tid * 8;

  const int wr = wid >> 1, wc = wid & 1;   // wave tile: 64(m) x 32(n)
  const int fr = lane & 15, q = lane >> 4;
  const int xm = fr & 7;                   // row&7 for all frag rows (offsets are mult of 8)

  f32x4 acc[4][2] = {};

  auto stage = [&](int buf, int kt) {
#pragma unroll
    for (int r = 0; r < 4; ++r)
      gload16(Ab + (size_t)arow[r] * S.lda + kt + acol[r], &As[buf][adst[r]]);
    gload16(Bb + (size_t)brow * S.ldw + kt + bcol, &Bs[buf][bdst]);
  };

  stage(0, 0);
  __syncthreads();

  for (int t = 0; t < kSteps; ++t) {
    if (t + 1 < kSteps) stage((t + 1) & 1, (t + 1) * 64);
    const __hip_bfloat16* Ac = As[t & 1];
    const __hip_bfloat16* Bc = Bs[t & 1];
#pragma unroll
    for (int ks = 0; ks < 2; ++ks) {
      const int cc = ks * 4 + q;
      const int co = ((cc ^ xm) << 3);
      short8v a0 = *(const short8v*)&Ac[(wr * 64 +  0 + fr) * 64 + co];
      short8v a1 = *(const short8v*)&Ac[(wr * 64 + 16 + fr) * 64 + co];
      short8v a2 = *(const short8v*)&Ac[(wr * 64 + 32 + fr) * 64 + co];
      short8v a3 = *(const short8v*)&Ac[(wr * 64 + 48 + fr) * 64 + co];
      short8v b0 = *(const short8v*)&Bc[(wc * 32 +  0 + fr) * 64 + co];
      short8v b1 = *(const short8v*)&Bc[(wc * 32 + 16 + fr) * 64 + co];
      acc[0][0] = __builtin_amdgcn_mfma_f32_16x16x32_bf16(a0, b0, acc[0][0], 0, 0, 0);
      acc[0][1] = __builtin_amdgcn_mfma_f32_16x16x32_bf16(a0, b1, acc[0][1], 0, 0, 0);
      acc[1][0] = __builtin_amdgcn_mfma_f32_16x16x32_bf16(a1, b0, acc[1][0], 0, 0, 0);
      acc[1][1] = __builtin_amdgcn_mfma_f32_16x16x32_bf16(a1, b1, acc[1][1], 0, 0, 0);
      acc[2][0] = __builtin_amdgcn_mfma_f32_16x16x32_bf16(a2, b0, acc[2][0], 0, 0, 0);
      acc[2][1] = __builtin_amdgcn_mfma_f32_16x16x32_bf16(a2, b1, acc[2][1], 0, 0, 0);
      acc[3][0] = __builtin_amdgcn_mfma_f32_16x16x32_bf16(a3, b0, acc[3][0], 0, 0, 0);
      acc[3][1] = __builtin_amdgcn_mfma_f32_16x16x32_bf16(a3, b1, acc[3][1], 0, 0, 0);
    }
    __syncthreads();
  }

#pragma unroll
  for (int i = 0; i < 4; ++i) {
    const int mb = m0 + wr * 64 + i * 16 + q * 4;
#pragma unroll
    for (int j = 0; j < 2; ++j) {
      const int n = n0 + wc * 32 + j * 16 + fr;
      if (n >= Nlim) continue;
      if (ATOMIC) {
#pragma unroll
        for (int v = 0; v < 4; ++v)
          atomicAdd(&S.C[(size_t)(mb + v) * S.ldc + n], acc[i][j][v]);
      } else {
        const float bb = S.bias[n];
#pragma unroll
        for (int v = 0; v < 4; ++v) {
          float val = acc[i][j][v] + bb;
          if (ACT) val = fmaxf(val, 0.f);
          if (S.C)  S.C[(size_t)(mb + v) * S.ldc + n] = val;
          if (S.Cb) S.Cb[(size_t)(mb + v) * S.ldcb + n] = __float2bfloat16(val);
        }
      }
    }
  }
}

// ---------------- fused fp32->bf16 conversion of all weights -----------------
struct CvtTable {
  const float* src[15];
  __hip_bfloat16* dst[15];
  long nchunk[15];          // Npad*Kdst/8 per segment
  int srcld[15], N[15], Kdst[15], Kval[15];
  int cumBlk[16];           // starting block of each segment
};

__global__ __launch_bounds__(256)
void k_cvt_all(CvtTable T)
{
  const int bx = blockIdx.x;
  int sg = 0;
#pragma unroll
  for (int i = 1; i < 15; ++i) sg += (bx >= T.cumBlk[i]) ? 1 : 0;
  const float* src = T.src[0]; __hip_bfloat16* dst = T.dst[0];
  long nchunk = T.nchunk[0];
  int srcld = T.srcld[0], N = T.N[0], Kd = T.Kdst[0], Kv = T.Kval[0], b0 = T.cumBlk[0];
#pragma unroll
  for (int i = 1; i < 15; ++i)
    if (sg == i) { src = T.src[i]; dst = T.dst[i]; nchunk = T.nchunk[i];
                   srcld = T.srcld[i]; N = T.N[i]; Kd = T.Kdst[i]; Kv = T.Kval[i]; b0 = T.cumBlk[i]; }
  long chunk = (long)(bx - b0) * 256 + threadIdx.x;
  if (chunk >= nchunk) return;
  long idx = chunk * 8;
  int n = (int)(idx / Kd);
  int k = (int)(idx % Kd);
  uint4 o;
  if (n < N && k < Kv) {
    const float* s = src + (size_t)n * srcld + k;
    float4 v0 = *(const float4*)s;
    float4 v1 = *(const float4*)(s + 4);
    o.x = bfbits(v0.x) | (bfbits(v0.y) << 16);
    o.y = bfbits(v0.z) | (bfbits(v0.w) << 16);
    o.z = bfbits(v1.x) | (bfbits(v1.y) << 16);
    o.w = bfbits(v1.z) | (bfbits(v1.w) << 16);
  } else {
    o = make_uint4(0, 0, 0, 0);
  }
  *(uint4*)(dst + idx) = o;
}

// ---------------- GRU elementwise (fp32 math, dual fp32+bf16 out) ----------------
__global__ __launch_bounds__(256)
void k_gru(const float* __restrict__ gi, const float* __restrict__ gh,
           const float* __restrict__ hs, int ldsrc,
           float* __restrict__ hd, int lddst, __hip_bfloat16* __restrict__ hb)
{
  int idx = blockIdx.x * 256 + threadIdx.x;     // 256*1024
  int b = idx >> 10, j = idx & 1023;
  float ir = gi[b * 3072 + j];
  float iz = gi[b * 3072 + 1024 + j];
  float in_ = gi[b * 3072 + 2048 + j];
  float hr = gh[b * 3072 + j];
  float hz = gh[b * 3072 + 1024 + j];
  float hn = gh[b * 3072 + 2048 + j];
  float r = 1.f / (1.f + expf(-(ir + hr)));
  float z = 1.f / (1.f + expf(-(iz + hz)));
  float n = tanhf(in_ + r * hn);
  float h = hs[(size_t)b * ldsrc + j];
  float o = (1.f - z) * n + z * h;
  hd[(size_t)b * lddst + j] = o;
  hb[idx] = __float2bfloat16(o);
}

// softmax over 64-wide groups of q (bf16, stride QN), scatter (bf16) into x2
__global__ __launch_bounds__(256)
void k_softmax_scatter(const __hip_bfloat16* __restrict__ q, __hip_bfloat16* __restrict__ x2)
{
  int wid = blockIdx.x * 4 + (threadIdx.x >> 6);
  int lane = threadIdx.x & 63;
  int b = wid / 255, p = wid % 255;
  float v = __bfloat162float(q[(size_t)b * QN + p * 64 + lane]);
  float m = v;
#pragma unroll
  for (int s = 32; s; s >>= 1) m = fmaxf(m, __shfl_xor(m, s));
  float e = expf(v - m);
  float sum = e;
#pragma unroll
  for (int s = 32; s; s >>= 1) sum += __shfl_xor(sum, s);
  float r = e / sum;
  int flat = p * 16384 + b * 64 + lane;
  int bp = flat / QN;
  int j = flat - bp * QN;
  x2[(size_t)bp * X2W + j] = __float2bfloat16(r);
}

__global__ __launch_bounds__(256)
void k_x2_tail(const __hip_bfloat16* __restrict__ taus_t, __hip_bfloat16* __restrict__ x2)
{
  int idx = blockIdx.x * 256 + threadIdx.x;   // 256*576
  int b = idx / TAU, c = idx % TAU;
  if (c < 64)
    x2[(size_t)b * X2W + QN + c] = taus_t[(size_t)b * TAUP + OBS + c];
  else
    x2[(size_t)b * X2W + QN + 64 + (c - 64)] = taus_t[(size_t)b * TAUP + (c - 64)];
}

__global__ __launch_bounds__(256)
void k_concat_pi_loop(const __hip_bfloat16* __restrict__ taus_t,
                      const __hip_bfloat16* __restrict__ msg,
                      __hip_bfloat16* __restrict__ piin)
{
  int idx = blockIdx.x * 256 + threadIdx.x;   // 256*2560
  int b = idx / PIW, c = idx % PIW;
  piin[idx] = (c < OBS) ? taus_t[(size_t)b * TAUP + c] : msg[b * MSG + (c - OBS)];
}

__global__ __launch_bounds__(256)
void k_concat_pi_final(const float* __restrict__ in, const float* __restrict__ nm,
                       __hip_bfloat16* __restrict__ piin)
{
  int idx = blockIdx.x * 256 + threadIdx.x;
  int b = idx / PIW, c = idx % PIW;
  float v = (c < OBS) ? in[(size_t)b * INW + c] : nm[c - OBS];
  piin[idx] = __float2bfloat16(v);
}

__global__ __launch_bounds__(256)
void k_init_h(const float* __restrict__ hid,
              float* __restrict__ h32a, float* __restrict__ h32o, float* __restrict__ h32p,
              __hip_bfloat16* __restrict__ hba, __hip_bfloat16* __restrict__ hbo,
              __hip_bfloat16* __restrict__ hbp, __hip_bfloat16* __restrict__ hbp0)
{
  int idx = blockIdx.x * 256 + threadIdx.x;   // 256*3072
  int b = idx / 3072, c = idx % 3072;
  float v = hid[idx];
  __hip_bfloat16 hb = __float2bfloat16(v);
  int j = c & 1023;
  if (c < 1024)      { h32a[b * 1024 + j] = v; hba[b * 1024 + j] = hb; }
  else if (c < 2048) { h32o[b * 1024 + j] = v; hbo[b * 1024 + j] = hb; }
  else               { h32p[b * 1024 + j] = v; hbp[b * 1024 + j] = hb; hbp0[b * 1024 + j] = hb; }
}

// init all 3 taus slabs (stride TAUP): t=0 valid cols from inputs, everything else 0
__global__ __launch_bounds__(256)
void k_init_taus(const float* __restrict__ in, __hip_bfloat16* __restrict__ taus)
{
  int idx = blockIdx.x * 256 + threadIdx.x;   // 3*256*TAUP
  int t = idx / (256 * TAUP);
  int r = (idx / TAUP) % 256;
  int c = idx % TAUP;
  float v = 0.f;
  if (t == 0 && c < TAU)
    v = (c < OBS) ? in[(size_t)r * INW + OBS + c]
                  : in[(size_t)r * INW + 2 * OBS + (c - OBS)];
  taus[idx] = __float2bfloat16(v);
}

__global__ __launch_bounds__(256)
void k_fill_bias(float* __restrict__ C, const float* __restrict__ bias)
{
  int idx = blockIdx.x * 256 + threadIdx.x;   // 256*1024
  C[idx] = bias[idx & 1023];
}

__global__ __launch_bounds__(256)
void k_relu_cvt(const float* __restrict__ s, __hip_bfloat16* __restrict__ d)
{
  int idx = blockIdx.x * 256 + threadIdx.x;
  d[idx] = __float2bfloat16(fmaxf(s[idx], 0.f));
}

__global__ __launch_bounds__(64)
void k_vv(const __hip_bfloat16* __restrict__ taus, const float* __restrict__ w,
          const float* __restrict__ bias, float* __restrict__ vv)
{
  int row = blockIdx.x;        // 0..767
  int lane = threadIdx.x;
  const __hip_bfloat16* tr = taus + (size_t)row * TAUP;
  for (int v = 0; v < 8; ++v) {
    float s = 0.f;
    for (int k = lane; k < TAU; k += 64) s += __bfloat162float(tr[k]) * w[v * TAU + k];
#pragma unroll
    for (int d = 32; d; d >>= 1) s += __shfl_xor(s, d);
    if (lane == 0) vv[row * 8 + v] = s + bias[v];
  }
}

__global__ __launch_bounds__(64)
void k_attn(const float* __restrict__ qv, const float* __restrict__ kk,
            const float* __restrict__ vv, float* __restrict__ nm,
            float* __restrict__ out_q)
{
  int b = blockIdx.x;
  int lane = threadIdx.x;
  const float* qb = qv + (size_t)b * 1024;
  float s[3];
#pragma unroll
  for (int t = 0; t < 3; ++t) {
    const float* kb = kk + (size_t)(t * 256 + b) * 1024;
    float acc = 0.f;
    for (int h = lane; h < 1024; h += 64) acc += qb[h] * kb[h];
#pragma unroll
    for (int d = 32; d; d >>= 1) acc += __shfl_xor(acc, d);
    s[t] = acc * (1.f / 32.f);
  }
  float m = fmaxf(s[0], fmaxf(s[1], s[2]));
  float e0 = expf(s[0] - m), e1 = expf(s[1] - m), e2 = expf(s[2] - m);
  float inv = 1.f / (e0 + e1 + e2);
  float a0 = e0 * inv, a1 = e1 * inv, a2 = e2 * inv;
  if (lane < 8) {
    float v = a0 * vv[(0 * 256 + b) * 8 + lane]
            + a1 * vv[(1 * 256 + b) * 8 + lane]
            + a2 * vv[(2 * 256 + b) * 8 + lane];
    nm[b * 8 + lane] = v;
    out_q[b * 72 + lane] = v;
  }
}

__global__ __launch_bounds__(256)
void k_copy_hout(const float* __restrict__ hfa, const float* __restrict__ hfo,
                 float* __restrict__ hout)
{
  int idx = blockIdx.x * 256 + threadIdx.x;   // 256*2048
  int b = idx / 2048, c = idx % 2048;
  float v = (c < 1024) ? hfa[b * 1024 + c] : hfo[b * 1024 + (c - 1024)];
  hout[(size_t)b * 3072 + c] = v;
}

extern "C" void kernel_launch(void* const* d_in, const int* in_sizes, int n_in,
                              void* d_out_v, int out_size, void* d_ws, size_t ws_size,
                              hipStream_t stream)
{
  const float* inputs   = (const float*)d_in[0];
  const float* hidden   = (const float*)d_in[1];
  const float* pi_fc1_w = (const float*)d_in[2];
  const float* pi_fc1_b = (const float*)d_in[3];
  const float* pi_fc2_w = (const float*)d_in[4];
  const float* pi_fc2_b = (const float*)d_in[5];
  const float* fa_fc1_w = (const float*)d_in[6];
  const float* fa_fc1_b = (const float*)d_in[7];
  const float* fa_fc2_w = (const float*)d_in[8];
  const float* fa_fc2_b = (const float*)d_in[9];
  const float* fo_fc1_w = (const float*)d_in[10];
  const float* fo_fc1_b = (const float*)d_in[11];
  const float* fo_fc2_w = (const float*)d_in[12];
  const float* fo_fc2_b = (const float*)d_in[13];
  const float* am_qs_w  = (const float*)d_in[14];
  const float* am_qs_b  = (const float*)d_in[15];
  const float* am_ks_w  = (const float*)d_in[16];
  const float* am_ks_b  = (const float*)d_in[17];
  const float* am_vs_w  = (const float*)d_in[18];
  const float* am_vs_b  = (const float*)d_in[19];
  const float* pi_wih   = (const float*)d_in[20];
  const float* pi_bih   = (const float*)d_in[21];
  const float* pi_whh   = (const float*)d_in[22];
  const float* pi_bhh   = (const float*)d_in[23];
  const float* fa_wih   = (const float*)d_in[24];
  const float* fa_bih   = (const float*)d_in[25];
  const float* fa_whh   = (const float*)d_in[26];
  const float* fa_bhh   = (const float*)d_in[27];
  const float* fo_wih   = (const float*)d_in[28];
  const float* fo_bih   = (const float*)d_in[29];
  const float* fo_whh   = (const float*)d_in[30];
  const float* fo_bhh   = (const float*)d_in[31];

  float* out = (float*)d_out_v;
  char* p = (char*)d_ws;
  auto alloc = [&](size_t bytes) { void* r = p; p += (bytes + 255) & ~(size_t)255; return r; };
  typedef __hip_bfloat16 bf;

  // bf16 weights
  bf* WPI1 = (bf*)alloc((size_t)1024 * 2560 * 2);
  bf* WPI2 = (bf*)alloc((size_t)64 * 1024 * 2);
  bf* WFA1 = (bf*)alloc((size_t)1024 * 512 * 2);
  bf* WFA2 = (bf*)alloc((size_t)16384 * 1024 * 2);
  bf* WFO1 = (bf*)alloc((size_t)1024 * 16896 * 2);
  bf* WFO2 = (bf*)alloc((size_t)512 * 1024 * 2);
  bf* WQS  = (bf*)alloc((size_t)1024 * 2048 * 2);
  bf* WKS  = (bf*)alloc((size_t)1024 * TAUP * 2);
  bf* WPIIH = (bf*)alloc((size_t)3072 * 1024 * 2);
  bf* WPIHH = (bf*)alloc((size_t)3072 * 1024 * 2);
  bf* WFAIH = (bf*)alloc((size_t)3072 * 1024 * 2);
  bf* WFAHH = (bf*)alloc((size_t)3072 * 1024 * 2);
  bf* WFOIH = (bf*)alloc((size_t)3072 * 1024 * 2);
  bf* WFOHH = (bf*)alloc((size_t)3072 * 1024 * 2);
  // bf16 activations
  bf* HFAB = (bf*)alloc((size_t)256 * 1024 * 2);
  bf* HFOB = (bf*)alloc((size_t)256 * 1024 * 2);
  bf* HPIB = (bf*)alloc((size_t)256 * 1024 * 2);
  bf* HPI0B = (bf*)alloc((size_t)256 * 1024 * 2);
  bf* XBUFB = (bf*)alloc((size_t)256 * 1024 * 2);
  bf* TAUSB = (bf*)alloc((size_t)3 * 256 * TAUP * 2);
  bf* X2B  = (bf*)alloc((size_t)256 * X2W * 2);
  bf* PIINB = (bf*)alloc((size_t)256 * PIW * 2);
  bf* MSGB = (bf*)alloc((size_t)256 * MSG * 2);
  bf* QBUFB = (bf*)alloc((size_t)256 * QN * 2);
  // fp32
  float* HFA32 = (float*)alloc((size_t)256 * 1024 * 4);
  float* HFO32 = (float*)alloc((size_t)256 * 1024 * 4);
  float* HPI32 = (float*)alloc((size_t)256 * 1024 * 4);
  float* XBUF32 = (float*)alloc((size_t)256 * 1024 * 4);
  float* GI = (float*)alloc((size_t)256 * 3072 * 4);
  float* GH = (float*)alloc((size_t)256 * 3072 * 4);
  float* QV = (float*)alloc((size_t)256 * 1024 * 4);
  float* KK = (float*)alloc((size_t)768 * 1024 * 4);
  float* VV = (float*)alloc((size_t)768 * 8 * 4);
  float* NM = (float*)alloc((size_t)2048 * 4);

  // ---- fused conversion table ----
  CvtTable T;
  int nseg = 0; int blk = 0;
  auto addseg = [&](const float* src, int srcld, bf* dst, int N, int Kdst, int Kval, int Npad) {
    long ch = (long)Npad * Kdst / 8;
    T.src[nseg] = src; T.dst[nseg] = dst; T.nchunk[nseg] = ch;
    T.srcld[nseg] = srcld; T.N[nseg] = N; T.Kdst[nseg] = Kdst; T.Kval[nseg] = Kval;
    T.cumBlk[nseg] = blk;
    blk += (int)((ch + 255) / 256);
    ++nseg;
  };
  addseg(pi_fc1_w, 2560, WPI1, 1024, 2560, 2560, 1024);
  addseg(pi_fc2_w, 1024, WPI2, 64, 1024, 1024, 64);
  addseg(fa_fc1_w, 512,  WFA1, 1024, 512, 512, 1024);
  addseg(fa_fc2_w, 1024, WFA2, 16320, 1024, 1024, 16384);
  addseg(fo_fc1_w, 16896, WFO1, 1024, 16896, 16896, 1024);
  addseg(fo_fc2_w, 1024, WFO2, 512, 1024, 1024, 512);
  addseg(am_qs_w, 2048, WQS, 1024, 2048, 2048, 1024);
  addseg(am_ks_w, 576, WKS, 1024, TAUP, 576, 1024);
  addseg(pi_wih, 1024, WPIIH, 3072, 1024, 1024, 3072);
  addseg(pi_whh, 1024, WPIHH, 3072, 1024, 1024, 3072);
  addseg(fa_wih, 1024, WFAIH, 3072, 1024, 1024, 3072);
  addseg(fa_whh, 1024, WFAHH, 3072, 1024, 1024, 3072);
  addseg(fo_wih, 1024, WFOIH, 3072, 1024, 1024, 3072);
  addseg(fo_whh, 1024, WFOHH, 3072, 1024, 1024, 3072);
  addseg(inputs + 1088, INW, MSGB, 256, 2048, 2048, 256);
  T.cumBlk[15] = blk;

  auto mset = [&](const bf* A, int lda, const bf* W, int ldw, const float* bias,
                  float* C, int ldc, bf* Cb, int ldcb) {
    MMSet s; s.A = A; s.W = W; s.bias = bias; s.C = C; s.Cb = Cb;
    s.lda = lda; s.ldw = ldw; s.ldc = ldc; s.ldcb = ldcb; return s;
  };
  auto mm = [&](MMSet a, int M, int Npad, int Nlim, int K, int act) {
    dim3 g(Npad / 64, M / 256, 1);
    if (act) k_mm<1, false, false><<<g, 512, 0, stream>>>(a, a, Nlim, K / 64);
    else     k_mm<0, false, false><<<g, 512, 0, stream>>>(a, a, Nlim, K / 64);
  };
  auto mmDual = [&](MMSet a, MMSet b, int Npad, int K) {
    dim3 g(Npad / 64, 1, 2);
    k_mm<0, false, true><<<g, 512, 0, stream>>>(a, b, Npad, K / 64);
  };

  k_cvt_all<<<blk, 256, 0, stream>>>(T);
  k_init_h<<<3072, 256, 0, stream>>>(hidden, HFA32, HFO32, HPI32, HFAB, HFOB, HPIB, HPI0B);
  k_init_taus<<<3 * TAUP, 256, 0, stream>>>(inputs, TAUSB);

  for (int t = 0; t < 2; ++t) {
    bf* taus_t = TAUSB + (size_t)t * 256 * TAUP;
    bf* taus_n = TAUSB + (size_t)(t + 1) * 256 * TAUP;
    // fa branch
    mm(mset(taus_t, TAUP, WFA1, 512, fa_fc1_b, nullptr, 0, XBUFB, 1024), 256, 1024, 1024, 512, 1);
    mmDual(mset(XBUFB, 1024, WFAIH, 1024, fa_bih, GI, 3072, nullptr, 0),
           mset(HFAB, 1024, WFAHH, 1024, fa_bhh, GH, 3072, nullptr, 0), 3072, 1024);
    k_gru<<<1024, 256, 0, stream>>>(GI, GH, HFA32, 1024, HFA32, 1024, HFAB);
    mm(mset(HFAB, 1024, WFA2, 1024, fa_fc2_b, nullptr, 0, QBUFB, QN), 256, 16384, QN, 1024, 0);
    // x2 = [scrambled softmax | a | o]
    k_x2_tail<<<576, 256, 0, stream>>>(taus_t, X2B);
    k_softmax_scatter<<<16320, 256, 0, stream>>>(QBUFB, X2B);
    // fo branch: split-K (z=12, 22 steps each), fp32 atomics onto bias-prefilled buf
    k_fill_bias<<<1024, 256, 0, stream>>>(XBUF32, fo_fc1_b);
    {
      dim3 g(16, 1, 12);
      MMSet s = mset(X2B, X2W, WFO1, X2W, fo_fc1_b, XBUF32, 1024, nullptr, 0);
      k_mm<0, true, false><<<g, 512, 0, stream>>>(s, s, 1024, 22);
    }
    k_relu_cvt<<<1024, 256, 0, stream>>>(XBUF32, XBUFB);
    mmDual(mset(XBUFB, 1024, WFOIH, 1024, fo_bih, GI, 3072, nullptr, 0),
           mset(HFOB, 1024, WFOHH, 1024, fo_bhh, GH, 3072, nullptr, 0), 3072, 1024);
    k_gru<<<1024, 256, 0, stream>>>(GI, GH, HFO32, 1024, HFO32, 1024, HFOB);
    mm(mset(HFOB, 1024, WFO2, 1024, fo_fc2_b, nullptr, 0, taus_n, TAUP), 256, 512, 512, 1024, 0);
    // pi branch
    k_concat_pi_loop<<<2560, 256, 0, stream>>>(taus_t, MSGB, PIINB);
    mm(mset(PIINB, PIW, WPI1, PIW, pi_fc1_b, nullptr, 0, XBUFB, 1024), 256, 1024, 1024, PIW, 1);
    mmDual(mset(XBUFB, 1024, WPIIH, 1024, pi_bih, GI, 3072, nullptr, 0),
           mset(HPIB, 1024, WPIHH, 1024, pi_bhh, GH, 3072, nullptr, 0), 3072, 1024);
    k_gru<<<1024, 256, 0, stream>>>(GI, GH, HPI32, 1024, HPI32, 1024, HPIB);
    mm(mset(HPIB, 1024, WPI2, 1024, pi_fc2_b, nullptr, 0, taus_n + OBS, TAUP), 256, 64, 64, 1024, 0);
  }

  // attention
  mm(mset(MSGB, MSG, WQS, MSG, am_qs_b, QV, 1024, nullptr, 0), 256, 1024, 1024, 2048, 0);
  mm(mset(TAUSB, TAUP, WKS, TAUP, am_ks_b, KK, 1024, nullptr, 0), 768, 1024, 1024, TAUP, 0);
  k_vv<<<768, 64, 0, stream>>>(TAUSB, am_vs_w, am_vs_b, VV);
  k_attn<<<256, 64, 0, stream>>>(QV, KK, VV, NM, out);

  // final pi with original h_pi0
  k_concat_pi_final<<<2560, 256, 0, stream>>>(inputs, NM, PIINB);
  mm(mset(PIINB, PIW, WPI1, PIW, pi_fc1_b, nullptr, 0, XBUFB, 1024), 256, 1024, 1024, PIW, 1);
  mmDual(mset(XBUFB, 1024, WPIIH, 1024, pi_bih, GI, 3072, nullptr, 0),
         mset(HPI0B, 1024, WPIHH, 1024, pi_bhh, GH, 3072, nullptr, 0), 3072, 1024);
  k_gru<<<1024, 256, 0, stream>>>(GI, GH, hidden + 2048, 3072,
                                  out + 256 * 72 + 2048, 3072, HPIB);
  mm(mset(HPIB, 1024, WPI2, 1024, pi_fc2_b, out + 8, 72, nullptr, 0), 256, 64, 64, 1024, 0);
  k_copy_hout<<<2048, 256, 0, stream>>>(HFA32, HFO32, out + 256 * 72);
  (void)in_sizes; (void)n_in; (void)out_size; (void)ws_size;
}

// Round 5
// 611.911 us; speedup vs baseline: 1.2042x; 1.2042x over previous
//
#include <hip/hip_runtime.h>
#include <hip/hip_bf16.h>
#include <math.h>

#define OBS 512
#define MSG 2048
#define TAU 576
#define TAUP 640      // padded taus row stride
#define QN 16320
#define X2W 16896
#define INW 3136
#define PIW 2560

typedef short short8v __attribute__((ext_vector_type(8)));
typedef float f32x4 __attribute__((ext_vector_type(4)));

__device__ inline unsigned short bfbits(float x) {
  __hip_bfloat16 h = __float2bfloat16(x);
  return *reinterpret_cast<unsigned short*>(&h);
}

__device__ inline void gload16(const void* g, void* l) {
  __builtin_amdgcn_global_load_lds((__attribute__((address_space(1))) void*)(g),
                                   (__attribute__((address_space(3))) void*)(l), 16, 0, 0);
}

// ---------------- bf16-MFMA NT matmul with on-the-fly fp32->bf16 W conversion --------
// C[m,n] = act(sum_k A[m,k]*W[n,k] + bias[n]); A bf16 (M x K, lda), W fp32 (N x K, ldw).
// BN=64, BK=64, 8 waves (4 wr x 2 wc). A staged via global_load_lds (pre-swizzled src);
// W reg-staged (issue-early / cvt+ds_write-late) into XOR-swizzled LDS.
// ATOMIC: split-K fp32 atomics via blockIdx.z. DUAL: blockIdx.z picks set (GRU pairs).
struct MMSet {
  const __hip_bfloat16* A;
  const float* W;
  const float* bias;
  float* C;
  __hip_bfloat16* Cb;
  int lda, ldw, ldc, ldcb;
};

template<int BM, int ACT, bool ATOMIC, bool DUAL>
__global__ __launch_bounds__(512)
void k_mm(MMSet s0, MMSet s1, int kSteps)
{
  constexpr int AREP = BM / 64;
  __shared__ __hip_bfloat16 As[2][BM * 64];
  __shared__ __hip_bfloat16 Bs[2][64 * 64];
  const MMSet S = (DUAL && blockIdx.z) ? s1 : s0;
  const int tid = threadIdx.x;
  const int lane = tid & 63;
  const int wid = tid >> 6;
  const int m0 = blockIdx.y * BM;
  const int n0 = blockIdx.x * 64;
  const size_t k0 = ATOMIC ? (size_t)blockIdx.z * kSteps * 64 : 0;

  const __hip_bfloat16* Ab = S.A + (size_t)m0 * S.lda + k0;
  const float* Bb = S.W + (size_t)n0 * S.ldw + k0;

  // A staging map: BM*8 chunks of 16B (8 bf16); LDS linear, global col XOR-swizzled.
  int arow[AREP], acol[AREP], adst[AREP];
#pragma unroll
  for (int r = 0; r < AREP; ++r) {
    int chunk = r * 512 + tid;
    arow[r] = chunk >> 3;
    acol[r] = ((chunk & 7) ^ (arow[r] & 7)) * 8;
    adst[r] = chunk * 8;
  }
  // W staging map: 1024 fp32 chunks of 16B (4 floats); dest = swizzled 8B slot.
  int brow[2], bcol[2], bdst[2];
#pragma unroll
  for (int r = 0; r < 2; ++r) {
    int c = r * 512 + tid;
    brow[r] = c >> 4;
    int g = (c & 15) >> 1, half = c & 1;
    bcol[r] = (c & 15) * 4;
    bdst[r] = brow[r] * 64 + ((g ^ (brow[r] & 7)) << 3) + half * 4;
  }

  const int wr = wid >> 1, wc = wid & 1;
  const int fr = lane & 15, q = lane >> 4;
  const int xm = fr & 7;

  f32x4 acc[AREP][2] = {};
  float4 bv0, bv1;

  auto stageA = [&](int buf, int kt) {
#pragma unroll
    for (int r = 0; r < AREP; ++r)
      gload16(Ab + (size_t)arow[r] * S.lda + kt + acol[r], &As[buf][adst[r]]);
  };
  auto loadB = [&](int kt) {
    bv0 = *(const float4*)(Bb + (size_t)brow[0] * S.ldw + kt + bcol[0]);
    bv1 = *(const float4*)(Bb + (size_t)brow[1] * S.ldw + kt + bcol[1]);
  };
  auto writeB = [&](int buf) {
    ushort4 w0, w1;
    w0.x = bfbits(bv0.x); w0.y = bfbits(bv0.y); w0.z = bfbits(bv0.z); w0.w = bfbits(bv0.w);
    w1.x = bfbits(bv1.x); w1.y = bfbits(bv1.y); w1.z = bfbits(bv1.z); w1.w = bfbits(bv1.w);
    *(ushort4*)&Bs[buf][bdst[0]] = w0;
    *(ushort4*)&Bs[buf][bdst[1]] = w1;
  };

  stageA(0, 0);
  loadB(0);
  writeB(0);
  __syncthreads();

  for (int t = 0; t < kSteps; ++t) {
    const int buf = t & 1;
    if (t + 1 < kSteps) {
      stageA(buf ^ 1, (t + 1) * 64);   // async -> LDS
      loadB((t + 1) * 64);             // issue-early to regs
    }
    const __hip_bfloat16* Ac = As[buf];
    const __hip_bfloat16* Bc = Bs[buf];
#pragma unroll
    for (int ks = 0; ks < 2; ++ks) {
      const int cc = ks * 4 + q;
      const int co = ((cc ^ xm) << 3);
      short8v b0 = *(const short8v*)&Bc[(wc * 32 +  0 + fr) * 64 + co];
      short8v b1 = *(const short8v*)&Bc[(wc * 32 + 16 + fr) * 64 + co];
#pragma unroll
      for (int i = 0; i < AREP; ++i) {
        short8v a = *(const short8v*)&Ac[(wr * (AREP * 16) + i * 16 + fr) * 64 + co];
        acc[i][0] = __builtin_amdgcn_mfma_f32_16x16x32_bf16(a, b0, acc[i][0], 0, 0, 0);
        acc[i][1] = __builtin_amdgcn_mfma_f32_16x16x32_bf16(a, b1, acc[i][1], 0, 0, 0);
      }
    }
    if (t + 1 < kSteps) writeB(buf ^ 1);   // cvt + ds_write late (T14)
    __syncthreads();
  }

#pragma unroll
  for (int i = 0; i < AREP; ++i) {
    const int mb = m0 + wr * (AREP * 16) + i * 16 + q * 4;
#pragma unroll
    for (int j = 0; j < 2; ++j) {
      const int n = n0 + wc * 32 + j * 16 + fr;
      if (ATOMIC) {
#pragma unroll
        for (int v = 0; v < 4; ++v)
          atomicAdd(&S.C[(size_t)(mb + v) * S.ldc + n], acc[i][j][v]);
      } else {
        const float bb = S.bias[n];
#pragma unroll
        for (int v = 0; v < 4; ++v) {
          float val = acc[i][j][v] + bb;
          if (ACT) val = fmaxf(val, 0.f);
          if (S.C)  S.C[(size_t)(mb + v) * S.ldc + n] = val;
          if (S.Cb) S.Cb[(size_t)(mb + v) * S.ldcb + n] = __float2bfloat16(val);
        }
      }
    }
  }
}

// ---------------- fused init: hidden split + taus slabs + msg cvt ----------------
__global__ __launch_bounds__(256)
void k_init(const float* __restrict__ in, const float* __restrict__ hid,
            float* __restrict__ h32a, float* __restrict__ h32o, float* __restrict__ h32p,
            __hip_bfloat16* __restrict__ hba, __hip_bfloat16* __restrict__ hbo,
            __hip_bfloat16* __restrict__ hbp, __hip_bfloat16* __restrict__ hbp0,
            __hip_bfloat16* __restrict__ taus, __hip_bfloat16* __restrict__ msgb)
{
  const int bx = blockIdx.x;
  if (bx < 3072) {                       // hidden split: 256x3072
    int idx = bx * 256 + threadIdx.x;
    int b = idx / 3072, c = idx % 3072;
    float v = hid[idx];
    __hip_bfloat16 hb = __float2bfloat16(v);
    int j = c & 1023;
    if (c < 1024)      { h32a[b * 1024 + j] = v; hba[b * 1024 + j] = hb; }
    else if (c < 2048) { h32o[b * 1024 + j] = v; hbo[b * 1024 + j] = hb; }
    else               { h32p[b * 1024 + j] = v; hbp[b * 1024 + j] = hb; hbp0[b * 1024 + j] = hb; }
  } else if (bx < 3072 + 1920) {         // taus slabs: 3*256*TAUP
    int idx = (bx - 3072) * 256 + threadIdx.x;
    int t = idx / (256 * TAUP);
    int r = (idx / TAUP) % 256;
    int c = idx % TAUP;
    float v = 0.f;
    if (t == 0 && c < TAU)
      v = (c < OBS) ? in[(size_t)r * INW + OBS + c]
                    : in[(size_t)r * INW + 2 * OBS + (c - OBS)];
    taus[idx] = __float2bfloat16(v);
  } else {                               // msg cvt: 256x2048
    int idx = (bx - 3072 - 1920) * 256 + threadIdx.x;
    int b = idx >> 11, c = idx & 2047;
    msgb[idx] = __float2bfloat16(in[(size_t)b * INW + 1088 + c]);
  }
}

// ---------------- GRU elementwise (fp32 math, dual fp32+bf16 out) ----------------
__global__ __launch_bounds__(256)
void k_gru(const float* __restrict__ gi, const float* __restrict__ gh,
           const float* __restrict__ hs, int ldsrc,
           float* __restrict__ hd, int lddst, __hip_bfloat16* __restrict__ hb)
{
  int idx = blockIdx.x * 256 + threadIdx.x;     // 256*1024
  int b = idx >> 10, j = idx & 1023;
  float ir = gi[b * 3072 + j];
  float iz = gi[b * 3072 + 1024 + j];
  float in_ = gi[b * 3072 + 2048 + j];
  float hr = gh[b * 3072 + j];
  float hz = gh[b * 3072 + 1024 + j];
  float hn = gh[b * 3072 + 2048 + j];
  float r = 1.f / (1.f + expf(-(ir + hr)));
  float z = 1.f / (1.f + expf(-(iz + hz)));
  float n = tanhf(in_ + r * hn);
  float h = hs[(size_t)b * ldsrc + j];
  float o = (1.f - z) * n + z * h;
  hd[(size_t)b * lddst + j] = o;
  hb[idx] = __float2bfloat16(o);
}

// softmax over 64-wide groups of q (bf16, stride QN), scatter (bf16) into x2
__global__ __launch_bounds__(256)
void k_softmax_scatter(const __hip_bfloat16* __restrict__ q, __hip_bfloat16* __restrict__ x2)
{
  int wid = blockIdx.x * 4 + (threadIdx.x >> 6);
  int lane = threadIdx.x & 63;
  int b = wid / 255, p = wid % 255;
  float v = __bfloat162float(q[(size_t)b * QN + p * 64 + lane]);
  float m = v;
#pragma unroll
  for (int s = 32; s; s >>= 1) m = fmaxf(m, __shfl_xor(m, s));
  float e = expf(v - m);
  float sum = e;
#pragma unroll
  for (int s = 32; s; s >>= 1) sum += __shfl_xor(sum, s);
  float r = e / sum;
  int flat = p * 16384 + b * 64 + lane;
  int bp = flat / QN;
  int j = flat - bp * QN;
  x2[(size_t)bp * X2W + j] = __float2bfloat16(r);
}

__global__ __launch_bounds__(256)
void k_x2_tail(const __hip_bfloat16* __restrict__ taus_t, __hip_bfloat16* __restrict__ x2)
{
  int idx = blockIdx.x * 256 + threadIdx.x;   // 256*576
  int b = idx / TAU, c = idx % TAU;
  if (c < 64)
    x2[(size_t)b * X2W + QN + c] = taus_t[(size_t)b * TAUP + OBS + c];
  else
    x2[(size_t)b * X2W + QN + 64 + (c - 64)] = taus_t[(size_t)b * TAUP + (c - 64)];
}

__global__ __launch_bounds__(256)
void k_concat_pi_loop(const __hip_bfloat16* __restrict__ taus_t,
                      const __hip_bfloat16* __restrict__ msg,
                      __hip_bfloat16* __restrict__ piin)
{
  int idx = blockIdx.x * 256 + threadIdx.x;   // 256*2560
  int b = idx / PIW, c = idx % PIW;
  piin[idx] = (c < OBS) ? taus_t[(size_t)b * TAUP + c] : msg[b * MSG + (c - OBS)];
}

__global__ __launch_bounds__(256)
void k_concat_pi_final(const float* __restrict__ in, const float* __restrict__ nm,
                       __hip_bfloat16* __restrict__ piin)
{
  int idx = blockIdx.x * 256 + threadIdx.x;
  int b = idx / PIW, c = idx % PIW;
  float v = (c < OBS) ? in[(size_t)b * INW + c] : nm[c - OBS];
  piin[idx] = __float2bfloat16(v);
}

__global__ __launch_bounds__(256)
void k_fill_bias(float* __restrict__ C, const float* __restrict__ bias)
{
  int idx = blockIdx.x * 256 + threadIdx.x;   // 256*1024
  C[idx] = bias[idx & 1023];
}

__global__ __launch_bounds__(256)
void k_relu_cvt(const float* __restrict__ s, __hip_bfloat16* __restrict__ d)
{
  int idx = blockIdx.x * 256 + threadIdx.x;
  d[idx] = __float2bfloat16(fmaxf(s[idx], 0.f));
}

__global__ __launch_bounds__(64)
void k_vv(const __hip_bfloat16* __restrict__ taus, const float* __restrict__ w,
          const float* __restrict__ bias, float* __restrict__ vv)
{
  int row = blockIdx.x;        // 0..767
  int lane = threadIdx.x;
  const __hip_bfloat16* tr = taus + (size_t)row * TAUP;
  for (int v = 0; v < 8; ++v) {
    float s = 0.f;
    for (int k = lane; k < TAU; k += 64) s += __bfloat162float(tr[k]) * w[v * TAU + k];
#pragma unroll
    for (int d = 32; d; d >>= 1) s += __shfl_xor(s, d);
    if (lane == 0) vv[row * 8 + v] = s + bias[v];
  }
}

__global__ __launch_bounds__(64)
void k_attn(const float* __restrict__ qv, const float* __restrict__ kk,
            const float* __restrict__ vv, float* __restrict__ nm,
            float* __restrict__ out_q)
{
  int b = blockIdx.x;
  int lane = threadIdx.x;
  const float* qb = qv + (size_t)b * 1024;
  float s[3];
#pragma unroll
  for (int t = 0; t < 3; ++t) {
    const float* kb = kk + (size_t)(t * 256 + b) * 1024;
    float acc = 0.f;
    for (int h = lane; h < 1024; h += 64) acc += qb[h] * kb[h];
#pragma unroll
    for (int d = 32; d; d >>= 1) acc += __shfl_xor(acc, d);
    s[t] = acc * (1.f / 32.f);
  }
  float m = fmaxf(s[0], fmaxf(s[1], s[2]));
  float e0 = expf(s[0] - m), e1 = expf(s[1] - m), e2 = expf(s[2] - m);
  float inv = 1.f / (e0 + e1 + e2);
  float a0 = e0 * inv, a1 = e1 * inv, a2 = e2 * inv;
  if (lane < 8) {
    float v = a0 * vv[(0 * 256 + b) * 8 + lane]
            + a1 * vv[(1 * 256 + b) * 8 + lane]
            + a2 * vv[(2 * 256 + b) * 8 + lane];
    nm[b * 8 + lane] = v;
    out_q[b * 72 + lane] = v;
  }
}

__global__ __launch_bounds__(256)
void k_copy_hout(const float* __restrict__ hfa, const float* __restrict__ hfo,
                 float* __restrict__ hout)
{
  int idx = blockIdx.x * 256 + threadIdx.x;   // 256*2048
  int b = idx / 2048, c = idx % 2048;
  float v = (c < 1024) ? hfa[b * 1024 + c] : hfo[b * 1024 + (c - 1024)];
  hout[(size_t)b * 3072 + c] = v;
}

extern "C" void kernel_launch(void* const* d_in, const int* in_sizes, int n_in,
                              void* d_out_v, int out_size, void* d_ws, size_t ws_size,
                              hipStream_t stream)
{
  const float* inputs   = (const float*)d_in[0];
  const float* hidden   = (const float*)d_in[1];
  const float* pi_fc1_w = (const float*)d_in[2];
  const float* pi_fc1_b = (const float*)d_in[3];
  const float* pi_fc2_w = (const float*)d_in[4];
  const float* pi_fc2_b = (const float*)d_in[5];
  const float* fa_fc1_w = (const float*)d_in[6];
  const float* fa_fc1_b = (const float*)d_in[7];
  const float* fa_fc2_w = (const float*)d_in[8];
  const float* fa_fc2_b = (const float*)d_in[9];
  const float* fo_fc1_w = (const float*)d_in[10];
  const float* fo_fc1_b = (const float*)d_in[11];
  const float* fo_fc2_w = (const float*)d_in[12];
  const float* fo_fc2_b = (const float*)d_in[13];
  const float* am_qs_w  = (const float*)d_in[14];
  const float* am_qs_b  = (const float*)d_in[15];
  const float* am_ks_w  = (const float*)d_in[16];
  const float* am_ks_b  = (const float*)d_in[17];
  const float* am_vs_w  = (const float*)d_in[18];
  const float* am_vs_b  = (const float*)d_in[19];
  const float* pi_wih   = (const float*)d_in[20];
  const float* pi_bih   = (const float*)d_in[21];
  const float* pi_whh   = (const float*)d_in[22];
  const float* pi_bhh   = (const float*)d_in[23];
  const float* fa_wih   = (const float*)d_in[24];
  const float* fa_bih   = (const float*)d_in[25];
  const float* fa_whh   = (const float*)d_in[26];
  const float* fa_bhh   = (const float*)d_in[27];
  const float* fo_wih   = (const float*)d_in[28];
  const float* fo_bih   = (const float*)d_in[29];
  const float* fo_whh   = (const float*)d_in[30];
  const float* fo_bhh   = (const float*)d_in[31];

  float* out = (float*)d_out_v;
  char* p = (char*)d_ws;
  auto alloc = [&](size_t bytes) { void* r = p; p += (bytes + 255) & ~(size_t)255; return r; };
  typedef __hip_bfloat16 bf;

  // bf16 activations
  bf* HFAB = (bf*)alloc((size_t)256 * 1024 * 2);
  bf* HFOB = (bf*)alloc((size_t)256 * 1024 * 2);
  bf* HPIB = (bf*)alloc((size_t)256 * 1024 * 2);
  bf* HPI0B = (bf*)alloc((size_t)256 * 1024 * 2);
  bf* XBUFB = (bf*)alloc((size_t)256 * 1024 * 2);
  bf* TAUSB = (bf*)alloc((size_t)3 * 256 * TAUP * 2);
  bf* X2B  = (bf*)alloc((size_t)256 * X2W * 2);
  bf* PIINB = (bf*)alloc((size_t)256 * PIW * 2);
  bf* MSGB = (bf*)alloc((size_t)256 * MSG * 2);
  bf* QBUFB = (bf*)alloc((size_t)256 * QN * 2);
  // fp32
  float* HFA32 = (float*)alloc((size_t)256 * 1024 * 4);
  float* HFO32 = (float*)alloc((size_t)256 * 1024 * 4);
  float* HPI32 = (float*)alloc((size_t)256 * 1024 * 4);
  float* XBUF32 = (float*)alloc((size_t)256 * 1024 * 4);
  float* GI = (float*)alloc((size_t)256 * 3072 * 4);
  float* GH = (float*)alloc((size_t)256 * 3072 * 4);
  float* QV = (float*)alloc((size_t)256 * 1024 * 4);
  float* KK = (float*)alloc((size_t)768 * 1024 * 4);
  float* VV = (float*)alloc((size_t)768 * 8 * 4);
  float* NM = (float*)alloc((size_t)2048 * 4);

  auto mset = [&](const bf* A, int lda, const float* W, int ldw, const float* bias,
                  float* C, int ldc, bf* Cb, int ldcb) {
    MMSet s; s.A = A; s.W = W; s.bias = bias; s.C = C; s.Cb = Cb;
    s.lda = lda; s.ldw = ldw; s.ldc = ldc; s.ldcb = ldcb; return s;
  };
  auto mm256 = [&](MMSet a, int M, int N, int K) {
    dim3 g(N / 64, M / 256, 1);
    k_mm<256, 0, false, false><<<g, 512, 0, stream>>>(a, a, K / 64);
  };
  auto mm128 = [&](MMSet a, int M, int N, int K) {
    dim3 g(N / 64, M / 128, 1);
    k_mm<128, 0, false, false><<<g, 512, 0, stream>>>(a, a, K / 64);
  };
  auto mm64 = [&](MMSet a, int N, int K, int act) {
    dim3 g(N / 64, 4, 1);
    if (act) k_mm<64, 1, false, false><<<g, 512, 0, stream>>>(a, a, K / 64);
    else     k_mm<64, 0, false, false><<<g, 512, 0, stream>>>(a, a, K / 64);
  };
  auto mmDual = [&](MMSet a, MMSet b, int N, int K) {
    dim3 g(N / 64, 2, 2);
    k_mm<128, 0, false, true><<<g, 512, 0, stream>>>(a, b, K / 64);
  };

  k_init<<<3072 + 1920 + 2048, 256, 0, stream>>>(inputs, hidden,
      HFA32, HFO32, HPI32, HFAB, HFOB, HPIB, HPI0B, TAUSB, MSGB);

  for (int t = 0; t < 2; ++t) {
    bf* taus_t = TAUSB + (size_t)t * 256 * TAUP;
    bf* taus_n = TAUSB + (size_t)(t + 1) * 256 * TAUP;
    // fa branch
    mm64(mset(taus_t, TAUP, fa_fc1_w, 512, fa_fc1_b, nullptr, 0, XBUFB, 1024), 1024, 512, 1);
    mmDual(mset(XBUFB, 1024, fa_wih, 1024, fa_bih, GI, 3072, nullptr, 0),
           mset(HFAB, 1024, fa_whh, 1024, fa_bhh, GH, 3072, nullptr, 0), 3072, 1024);
    k_gru<<<1024, 256, 0, stream>>>(GI, GH, HFA32, 1024, HFA32, 1024, HFAB);
    mm256(mset(HFAB, 1024, fa_fc2_w, 1024, fa_fc2_b, nullptr, 0, QBUFB, QN), 256, QN, 1024);
    // x2 = [scrambled softmax | a | o]
    k_x2_tail<<<576, 256, 0, stream>>>(taus_t, X2B);
    k_softmax_scatter<<<16320, 256, 0, stream>>>(QBUFB, X2B);
    // fo branch: split-K (z=12 x 22 steps), fp32 atomics onto bias-prefilled buf
    k_fill_bias<<<1024, 256, 0, stream>>>(XBUF32, fo_fc1_b);
    {
      dim3 g(16, 1, 12);
      MMSet s = mset(X2B, X2W, fo_fc1_w, X2W, fo_fc1_b, XBUF32, 1024, nullptr, 0);
      k_mm<256, 0, true, false><<<g, 512, 0, stream>>>(s, s, 22);
    }
    k_relu_cvt<<<1024, 256, 0, stream>>>(XBUF32, XBUFB);
    mmDual(mset(XBUFB, 1024, fo_wih, 1024, fo_bih, GI, 3072, nullptr, 0),
           mset(HFOB, 1024, fo_whh, 1024, fo_bhh, GH, 3072, nullptr, 0), 3072, 1024);
    k_gru<<<1024, 256, 0, stream>>>(GI, GH, HFO32, 1024, HFO32, 1024, HFOB);
    mm64(mset(HFOB, 1024, fo_fc2_w, 1024, fo_fc2_b, nullptr, 0, taus_n, TAUP), 512, 1024, 0);
    // pi branch
    k_concat_pi_loop<<<2560, 256, 0, stream>>>(taus_t, MSGB, PIINB);
    mm64(mset(PIINB, PIW, pi_fc1_w, PIW, pi_fc1_b, nullptr, 0, XBUFB, 1024), 1024, PIW, 1);
    mmDual(mset(XBUFB, 1024, pi_wih, 1024, pi_bih, GI, 3072, nullptr, 0),
           mset(HPIB, 1024, pi_whh, 1024, pi_bhh, GH, 3072, nullptr, 0), 3072, 1024);
    k_gru<<<1024, 256, 0, stream>>>(GI, GH, HPI32, 1024, HPI32, 1024, HPIB);
    mm64(mset(HPIB, 1024, pi_fc2_w, 1024, pi_fc2_b, nullptr, 0, taus_n + OBS, TAUP), 64, 1024, 0);
  }

  // attention
  mm64(mset(MSGB, MSG, am_qs_w, MSG, am_qs_b, QV, 1024, nullptr, 0), 1024, 2048, 0);
  mm128(mset(TAUSB, TAUP, am_ks_w, TAU, am_ks_b, KK, 1024, nullptr, 0), 768, 1024, TAU);
  k_vv<<<768, 64, 0, stream>>>(TAUSB, am_vs_w, am_vs_b, VV);
  k_attn<<<256, 64, 0, stream>>>(QV, KK, VV, NM, out);

  // final pi with original h_pi0
  k_concat_pi_final<<<2560, 256, 0, stream>>>(inputs, NM, PIINB);
  mm64(mset(PIINB, PIW, pi_fc1_w, PIW, pi_fc1_b, nullptr, 0, XBUFB, 1024), 1024, PIW, 1);
  mmDual(mset(XBUFB, 1024, pi_wih, 1024, pi_bih, GI, 3072, nullptr, 0),
         mset(HPI0B, 1024, pi_whh, 1024, pi_bhh, GH, 3072, nullptr, 0), 3072, 1024);
  k_gru<<<1024, 256, 0, stream>>>(GI, GH, hidden + 2048, 3072,
                                  out + 256 * 72 + 2048, 3072, HPIB);
  mm64(mset(HPIB, 1024, pi_fc2_w, 1024, pi_fc2_b, out + 8, 72, nullptr, 0), 64, 1024, 0);
  k_copy_hout<<<2048, 256, 0, stream>>>(HFA32, HFO32, out + 256 * 72);
  (void)in_sizes; (void)n_in; (void)out_size; (void)ws_size;
}